// Round 10
// baseline (410.427 us; speedup 1.0000x reference)
//
#include <hip/hip_runtime.h>
#include <hip/hip_bf16.h>

#define BB 4
#define SS 2048
#define DD 1024
#define HH 16
#define DHH 64
#define MM (BB*SS)   // 8192

typedef __bf16 bf16;
typedef __attribute__((ext_vector_type(4))) __bf16 bf16x4;
typedef __attribute__((ext_vector_type(8))) __bf16 bf16x8;
typedef __attribute__((ext_vector_type(4))) float floatx4;

#define C_SCALE 0.1803368801111164f   // 0.125 * log2(e), folded into Wq/bq

// async global->LDS DMA, 16 B per lane, lands at wave-uniform base + lane*16
#define GLD16(g, l) __builtin_amdgcn_global_load_lds( \
    (__attribute__((address_space(1))) void*)(g), \
    (__attribute__((address_space(3))) void*)(l), 16, 0, 0)

// ------------------------------------------------------------ x f32 -> bf16
__global__ __launch_bounds__(256) void cvt_k(const float* __restrict__ x,
                                             bf16* __restrict__ xc) {
    size_t o = ((size_t)blockIdx.x * 256 + threadIdx.x) * 8;
    float4 f0 = *(const float4*)(x + o);
    float4 f1 = *(const float4*)(x + o + 4);
    bf16x8 v;
    v[0] = (bf16)f0.x; v[1] = (bf16)f0.y; v[2] = (bf16)f0.z; v[3] = (bf16)f0.w;
    v[4] = (bf16)f1.x; v[5] = (bf16)f1.y; v[6] = (bf16)f1.z; v[7] = (bf16)f1.w;
    *(bf16x8*)(xc + o) = v;
}

// ------------------------------------------------------------ transpose
// Wt[z][n][k] = (bf16)(W[k][n] * scale), scale folds C_SCALE into Wq (z==0)
__global__ void transpose_k(const float* __restrict__ W0, const float* __restrict__ W1,
                            const float* __restrict__ W2, const float* __restrict__ W3,
                            bf16* __restrict__ Wt) {
    __shared__ bf16 tile[64][65];
    const float* W = (blockIdx.z == 0) ? W0 : (blockIdx.z == 1) ? W1
                    : (blockIdx.z == 2) ? W2 : W3;
    float sc = (blockIdx.z == 0) ? C_SCALE : 1.0f;
    bf16* Wo = Wt + (size_t)blockIdx.z * DD * DD;
    int bx = blockIdx.x * 64, by = blockIdx.y * 64;
    int tx = threadIdx.x & 63, ty = threadIdx.x >> 6;
    for (int i = ty; i < 64; i += 4)
        tile[i][tx] = (bf16)(W[(size_t)(by + i) * DD + bx + tx] * sc);
    __syncthreads();
    for (int i = ty; i < 64; i += 4)
        Wo[(size_t)(bx + i) * DD + by + tx] = tile[tx][i];
}

// ------------------------------------------------------------ bias concat (scale bq)
__global__ void bias_cat_k(const float* __restrict__ bq, const float* __restrict__ bk,
                           const float* __restrict__ bv, float* __restrict__ bcat) {
    int i = blockIdx.x * 256 + threadIdx.x;
    float v;
    if (i < 1024)      v = bq[i] * C_SCALE;
    else if (i < 2048) v = bk[i - 1024];
    else               v = bv[i - 2048];
    bcat[i] = v;
}

// ------------------------------------------------------------ 128x128 GEMM, BK=64
// la/lb hold two stacked BK=32 halves (GLD16 needs unpadded 64B-stride rows;
// 64B stride = 2-way bank alias = free).  Barrier rounds halved vs BK=32.
// out = A[m][k] * Bt[n][k] + bias[n]
// MODE 0: float out[m*DD+n]
// MODE 1: fused QKV routing; out base of contiguous Qb|Kb|Vb; which=n0>>10
//   Q,K: bf16 [((b*H+h)*S+s)*DH+dh]
//   V:   bf16 [((b*H+h)*DH+dh)*S + sigma(s)]  sigma = 4*(s&15)+((s>>4)&3) within 64-tile
template<int MODE>
__global__ __launch_bounds__(256) void gemm128_k(const bf16* __restrict__ A,
                                                 const bf16* __restrict__ Bt,
                                                 const float* __restrict__ bias,
                                                 void* __restrict__ outv) {
    __shared__ __align__(16) bf16 la[2][128 * 32];
    __shared__ __align__(16) bf16 lb[2][128 * 32];
    const int tid = threadIdx.x;
    const int l = tid & 63, w = tid >> 6;
    const int quad = l >> 4, lane16 = l & 15;
    const int wm = w >> 1, wn = w & 1;
    const int m0 = blockIdx.y * 128, n0 = blockIdx.x * 128;

    // staging: idx = w*4+j covers half=idx>>3, rows (idx&7)*16..+15, 16B/lane
    const bf16* Ag[4]; const bf16* Bg[4];
    bf16* Al[4]; bf16* Bl[4];
#pragma unroll
    for (int j = 0; j < 4; j++) {
        int idx = w * 4 + j;
        int half = idx >> 3, rb = idx & 7;
        int grow = rb * 16 + (l >> 2);
        int gcol = half * 32 + (l & 3) * 8;
        Ag[j] = A  + (size_t)(m0 + grow) * DD + gcol;
        Bg[j] = Bt + (size_t)(n0 + grow) * DD + gcol;
        int loff = half * (128 * 32) + grow * 32 + (l & 3) * 8;
        Al[j] = &la[0][0] + loff;
        Bl[j] = &lb[0][0] + loff;
    }

    floatx4 acc[4][4] = {};
    for (int k0 = 0; k0 < DD; k0 += 64) {
        __syncthreads();
#pragma unroll
        for (int j = 0; j < 4; j++) {
            GLD16(Ag[j] + k0, Al[j]);
            GLD16(Bg[j] + k0, Bl[j]);
        }
        __syncthreads();
#pragma unroll
        for (int kk = 0; kk < 2; kk++) {
            bf16x8 af[4], bfr[4];
#pragma unroll
            for (int mt = 0; mt < 4; mt++)
                af[mt] = *(const bf16x8*)(&la[kk][0] + (size_t)(wm * 64 + mt * 16 + lane16) * 32 + quad * 8);
#pragma unroll
            for (int nt = 0; nt < 4; nt++)
                bfr[nt] = *(const bf16x8*)(&lb[kk][0] + (size_t)(wn * 64 + nt * 16 + lane16) * 32 + quad * 8);
#pragma unroll
            for (int mt = 0; mt < 4; mt++)
#pragma unroll
                for (int nt = 0; nt < 4; nt++)
                    acc[mt][nt] = __builtin_amdgcn_mfma_f32_16x16x32_bf16(af[mt], bfr[nt], acc[mt][nt], 0, 0, 0);
        }
    }

    if (MODE == 0) {
        float* out = (float*)outv;
#pragma unroll
        for (int mt = 0; mt < 4; mt++)
#pragma unroll
            for (int nt = 0; nt < 4; nt++)
#pragma unroll
                for (int r = 0; r < 4; r++) {
                    int m = m0 + wm * 64 + mt * 16 + quad * 4 + r;
                    int n = n0 + wn * 64 + nt * 16 + lane16;
                    out[(size_t)m * DD + n] = acc[mt][nt][r] + bias[n];
                }
    } else {
        int which = n0 >> 10;
        bf16* dst = (bf16*)outv + (size_t)which * MM * DD;
#pragma unroll
        for (int mt = 0; mt < 4; mt++)
#pragma unroll
            for (int nt = 0; nt < 4; nt++)
#pragma unroll
                for (int r = 0; r < 4; r++) {
                    int m = m0 + wm * 64 + mt * 16 + quad * 4 + r;
                    int n = n0 + wn * 64 + nt * 16 + lane16;
                    float v = acc[mt][nt][r] + bias[n];
                    int n1 = n & 1023;
                    int b = m >> 11, s = m & (SS - 1);
                    int h = n1 >> 6, dh = n1 & 63;
                    if (which < 2) {
                        dst[((size_t)(b * HH + h) * SS + s) * DHH + dh] = (bf16)v;
                    } else {
                        int st = s & 63;
                        int sp = (s & ~63) | ((st & 15) * 4 + (st >> 4));   // sigma for packed P-store
                        dst[((size_t)(b * HH + h) * DHH + dh) * SS + sp] = (bf16)v;
                    }
                }
    }
}

// ------------------------------------------------------------ attention — barrier-free
// 128 queries/block, 32/wave (2 subtiles). K/V fragments loaded DIRECTLY from
// global (B-frag layout = 16B/lane segments; K+V total 32 MB < L3, tile 16 KB
// < L1 so the 4 waves/block mostly hit L1). No ks/vs LDS, no __syncthreads in
// the k-loop — only the per-wave ps round-trip with lgkmcnt(0) (DS ops are
// in-order per wave). R8 lesson: no forced waves-per-EU (spill).
// Q: [bh][s][dh] pre-scaled by 0.125*log2e   K: [bh][s][dh]
// Vt: [bh][dh][sigma(s)]   ctx: [b][s][h*DH+dh]
__global__ __launch_bounds__(256) void attn_k(const bf16* __restrict__ Q,
                                              const bf16* __restrict__ K,
                                              const bf16* __restrict__ Vt,
                                              bf16* __restrict__ ctx) {
    __shared__ __align__(16) bf16 ps[4][2][16 * 72];

    const int tid = threadIdx.x;
    const int l = tid & 63, w = tid >> 6;
    const int quad = l >> 4, lane16 = l & 15;
    const int qt = (blockIdx.x + 4 * (blockIdx.y >> 4)) & 15;
    const int bh = blockIdx.y;
    const int q0 = qt * 128;
    const bf16* Qp = Q  + (size_t)bh * SS * DHH;
    const bf16* Kp = K  + (size_t)bh * SS * DHH;
    const bf16* Vp = Vt + (size_t)bh * DHH * SS;

    // Q A-frags from global (one-time)
    bf16x8 qf[2][2];
#pragma unroll
    for (int sub = 0; sub < 2; sub++)
#pragma unroll
        for (int kk = 0; kk < 2; kk++)
            qf[sub][kk] = *(const bf16x8*)(
                Qp + (size_t)(q0 + w * 32 + sub * 16 + lane16) * DHH + kk * 32 + quad * 8);

    floatx4 o_acc[2][4] = {};
    float l_part[2][4] = {};
    const int qs0 = q0 + w * 32;
    const int qs1 = qs0 + 16;

    const int nkt = 2 * qt + 2;
    for (int kt = 0; kt < nkt; kt++) {
        const int kb0 = kt * 64;

        // K/V B-fragments straight from global
        bf16x8 kf[2][4], vf[2][4];
#pragma unroll
        for (int kk = 0; kk < 2; kk++)
#pragma unroll
            for (int nb = 0; nb < 4; nb++) {
                kf[kk][nb] = *(const bf16x8*)(
                    Kp + (size_t)(kb0 + nb * 16 + lane16) * DHH + kk * 32 + quad * 8);
                vf[kk][nb] = *(const bf16x8*)(
                    Vp + (size_t)(nb * 16 + lane16) * SS + kb0 + kk * 32 + quad * 8);
            }

#pragma unroll
        for (int sub = 0; sub < 2; sub++) {
            const int qsb = (sub == 0) ? qs0 : qs1;
            if (kb0 > qsb + 15) continue;           // fully masked (wave-uniform)

            floatx4 sc[4] = {};
#pragma unroll
            for (int nb = 0; nb < 4; nb++) {
                sc[nb] = __builtin_amdgcn_mfma_f32_16x16x32_bf16(qf[sub][0], kf[0][nb], sc[nb], 0, 0, 0);
                sc[nb] = __builtin_amdgcn_mfma_f32_16x16x32_bf16(qf[sub][1], kf[1][nb], sc[nb], 0, 0, 0);
            }

            // exp2 + mask + l partials fused with packed P-store
            // column sigma(key)=4*lane16+nb -> one b64 per row
            const bool diag = (kb0 + 63 > qsb);
#pragma unroll
            for (int r = 0; r < 4; r++) {
                bf16x4 pk;
#pragma unroll
                for (int nb = 0; nb < 4; nb++) {
                    float e = exp2f(sc[nb][r]);
                    if (diag) {
                        int key = kb0 + nb * 16 + lane16;
                        int qg  = qsb + quad * 4 + r;
                        e = (key <= qg) ? e : 0.f;
                    }
                    l_part[sub][r] += e;
                    pk[nb] = (bf16)e;
                }
                *(bf16x4*)(&ps[w][sub][(quad * 4 + r) * 72 + lane16 * 4]) = pk;
            }
            asm volatile("s_waitcnt lgkmcnt(0)" ::: "memory");

#pragma unroll
            for (int kk = 0; kk < 2; kk++) {
                bf16x8 af = *(const bf16x8*)(&ps[w][sub][lane16 * 72 + kk * 32 + quad * 8]);
#pragma unroll
                for (int nb = 0; nb < 4; nb++)
                    o_acc[sub][nb] = __builtin_amdgcn_mfma_f32_16x16x32_bf16(af, vf[kk][nb], o_acc[sub][nb], 0, 0, 0);
            }
        }
    }

#pragma unroll
    for (int off = 1; off < 16; off <<= 1)
#pragma unroll
        for (int sub = 0; sub < 2; sub++)
#pragma unroll
            for (int r = 0; r < 4; r++)
                l_part[sub][r] += __shfl_xor(l_part[sub][r], off, 64);

    int b = bh >> 4, h = bh & 15;
#pragma unroll
    for (int sub = 0; sub < 2; sub++)
#pragma unroll
        for (int r = 0; r < 4; r++) {
            float inv = 1.0f / l_part[sub][r];
            int s = q0 + w * 32 + sub * 16 + quad * 4 + r;
#pragma unroll
            for (int nb = 0; nb < 4; nb++) {
                int dh = nb * 16 + lane16;
                ctx[((size_t)(b * SS + s)) * DD + h * DHH + dh] = (bf16)(o_acc[sub][nb][r] * inv);
            }
        }
}

// ------------------------------------------------------------ launch
extern "C" void kernel_launch(void* const* d_in, const int* in_sizes, int n_in,
                              void* d_out, int out_size, void* d_ws, size_t ws_size,
                              hipStream_t stream) {
    const float* x  = (const float*)d_in[0];
    const float* Wq = (const float*)d_in[1];
    const float* bq = (const float*)d_in[2];
    const float* Wk = (const float*)d_in[3];
    const float* bk = (const float*)d_in[4];
    const float* Wv = (const float*)d_in[5];
    const float* bv = (const float*)d_in[6];
    const float* Wo = (const float*)d_in[7];
    const float* bo = (const float*)d_in[8];

    bf16* ws   = (bf16*)d_ws;
    bf16* xc   = ws;                               // 16 MB  x as bf16
    bf16* Wcat = xc + (size_t)MM * DD;             //  8 MB  [Wq^T*c | Wk^T | Wv^T | Wo^T]
    bf16* Qb   = Wcat + (size_t)4 * DD * DD;       // 16 MB each, contiguous Q|K|V
    bf16* Kb   = Qb + (size_t)MM * DD;
    bf16* Vb   = Kb + (size_t)MM * DD;
    bf16* Cb   = Vb + (size_t)MM * DD;             // 16 MB  context
    float* bcat = (float*)(Cb + (size_t)MM * DD);  // 12 KB

    cvt_k<<<dim3(MM * DD / 2048), dim3(256), 0, stream>>>(x, xc);
    transpose_k<<<dim3(16, 16, 4), dim3(256), 0, stream>>>(Wq, Wk, Wv, Wo, Wcat);
    bias_cat_k<<<dim3(12), dim3(256), 0, stream>>>(bq, bk, bv, bcat);

    gemm128_k<1><<<dim3(3 * DD / 128, MM / 128), dim3(256), 0, stream>>>(xc, Wcat, bcat, Qb);
    attn_k<<<dim3(SS / 128, BB * HH), dim3(256), 0, stream>>>(Qb, Kb, Vb, Cb);
    gemm128_k<0><<<dim3(DD / 128, MM / 128), dim3(256), 0, stream>>>(
        Cb, Wcat + (size_t)3 * DD * DD, bo, d_out);
}